// Round 1
// baseline (4475.164 us; speedup 1.0000x reference)
//
#include <hip/hip_runtime.h>
#include <hip/hip_bf16.h>
#include <cstdint>

#define B_ 512
#define T_ 100
#define STATE_ 200
#define LATENT_ 30
#define HIDDEN_ 200
#define EMBED_ 1024
#define ACT_ 6

// ---------------- helpers ----------------
__device__ __forceinline__ float bflo(unsigned int w){ return __uint_as_float(w << 16); }
__device__ __forceinline__ float bfhi(unsigned int w){ return __uint_as_float(w & 0xFFFF0000u); }

__device__ __forceinline__ float sigmoidf_(float x){ return 1.0f / (1.0f + expf(-x)); }

__device__ __forceinline__ float stdf_(float x){
  // softplus(x) + 0.1, clipped to [1e-6, 10]
  float sp = fmaxf(x, 0.0f) + log1pf(expf(-fabsf(x)));
  sp += 0.1f;
  return fminf(fmaxf(sp, 1e-6f), 10.0f);
}

// dual-row dot: bf16 weight row (length L, L%8==0, 16B aligned) vs two fp32 LDS vectors
template<int L>
__device__ __forceinline__ void dot2bf(const __hip_bfloat16* __restrict__ w,
                                       const float* __restrict__ v0,
                                       const float* __restrict__ v1,
                                       float& a0, float& a1){
  const uint4* wq = (const uint4*)w;
  #pragma unroll
  for (int c = 0; c < L/8; ++c){
    uint4 wv = wq[c];
    float4 p0 = *(const float4*)(v0 + c*8);
    float4 p1 = *(const float4*)(v0 + c*8 + 4);
    float4 q0 = *(const float4*)(v1 + c*8);
    float4 q1 = *(const float4*)(v1 + c*8 + 4);
    float w0=bflo(wv.x), w1=bfhi(wv.x), w2=bflo(wv.y), w3=bfhi(wv.y);
    float w4=bflo(wv.z), w5=bfhi(wv.z), w6=bflo(wv.w), w7=bfhi(wv.w);
    a0=fmaf(w0,p0.x,a0); a0=fmaf(w1,p0.y,a0); a0=fmaf(w2,p0.z,a0); a0=fmaf(w3,p0.w,a0);
    a0=fmaf(w4,p1.x,a0); a0=fmaf(w5,p1.y,a0); a0=fmaf(w6,p1.z,a0); a0=fmaf(w7,p1.w,a0);
    a1=fmaf(w0,q0.x,a1); a1=fmaf(w1,q0.y,a1); a1=fmaf(w2,q0.z,a1); a1=fmaf(w3,q0.w,a1);
    a1=fmaf(w4,q1.x,a1); a1=fmaf(w5,q1.y,a1); a1=fmaf(w6,q1.z,a1); a1=fmaf(w7,q1.w,a1);
  }
}

__device__ __forceinline__ float dotf32_200(const float* __restrict__ w,
                                            const float* __restrict__ v){
  float a = 0.f;
  #pragma unroll
  for (int c = 0; c < 50; ++c){
    float4 wv = *(const float4*)(w + c*4);
    float4 vv = *(const float4*)(v + c*4);
    a = fmaf(wv.x, vv.x, a); a = fmaf(wv.y, vv.y, a);
    a = fmaf(wv.z, vv.z, a); a = fmaf(wv.w, vv.w, a);
  }
  return a;
}

// bf16 weight buffer layout (element offsets):
//  Wla   [200][40]   @ 0        (lat_act_W padded 36->40, pad cols = 0)
//  Wih   [600][200]  @ 8000
//  Whh   [600][200]  @ 128000
//  Wp1h  [200][200]  @ 248000   (post1_W[:, :200])
//  Wpm   [30][200]   @ 288000
#define WOFF_LA 0
#define WOFF_IH 8000
#define WOFF_HH 128000
#define WOFF_P1 248000
#define WOFF_PM 288000
#define WTOT    294000

// ---------------- kernel 1: weight conversion to bf16 ----------------
__global__ __launch_bounds__(256) void prep_kernel(
    const float* __restrict__ lat_act_W,
    const float* __restrict__ gru_Wih,
    const float* __restrict__ gru_Whh,
    const float* __restrict__ post1_W,
    const float* __restrict__ post_m_W,
    __hip_bfloat16* __restrict__ wbuf)
{
  int idx = blockIdx.x * 256 + threadIdx.x;
  if (idx < WOFF_IH){
    int j = idx / 40, k = idx % 40;
    float v = (k < 36) ? lat_act_W[j*36 + k] : 0.0f;
    wbuf[idx] = __float2bfloat16(v);
  } else if (idx < WOFF_HH){
    wbuf[idx] = __float2bfloat16(gru_Wih[idx - WOFF_IH]);
  } else if (idx < WOFF_P1){
    wbuf[idx] = __float2bfloat16(gru_Whh[idx - WOFF_HH]);
  } else if (idx < WOFF_PM){
    int i = idx - WOFF_P1; int j = i / 200, k = i % 200;
    wbuf[idx] = __float2bfloat16(post1_W[(size_t)j*1224 + k]);
  } else if (idx < WTOT){
    wbuf[idx] = __float2bfloat16(post_m_W[idx - WOFF_PM]);
  }
}

// ---------------- kernel 2: Epost = e[:,1:] @ post1_W[:,200:].T + post1_b ----------------
// M = T*B = 51200 (m = t*512 + b), K = 1024, N = 200. fp32 tiled GEMM.
__global__ __launch_bounds__(256, 4) void epost_kernel(
    const float* __restrict__ e,
    const float* __restrict__ post1_W,
    const float* __restrict__ post1_b,
    float* __restrict__ Epost)
{
  __shared__ __align__(16) float As[32][36];   // 16B-aligned rows for float4 staging
  __shared__ float Ws[224][33];                // +1 pad: conflict-free scalar reads
  const int tid = threadIdx.x;
  const int m0 = blockIdx.x * 32;
  const int t  = m0 / B_;
  const int b0 = m0 % B_;
  const int tm = tid >> 5;    // 0..7
  const int tn = tid & 31;    // 0..31

  float acc[4][7];
  #pragma unroll
  for (int i = 0; i < 4; ++i)
    #pragma unroll
    for (int j = 0; j < 7; ++j) acc[i][j] = 0.f;

  for (int k0 = 0; k0 < EMBED_; k0 += 32){
    __syncthreads();
    {
      int r = tid >> 3, c = (tid & 7) * 4;
      const float* src = e + (((size_t)(b0 + r))*(T_+1) + (t + 1))*EMBED_ + k0 + c;
      *(float4*)&As[r][c] = *(const float4*)src;
    }
    for (int i = tid; i < 6400; i += 256){      // 200 rows x 32 k, scalar coalesced
      int n = i >> 5, k = i & 31;
      Ws[n][k] = post1_W[(size_t)n*1224 + 200 + k0 + k];
    }
    __syncthreads();
    #pragma unroll
    for (int k = 0; k < 32; ++k){
      float a0 = As[tm][k], a1 = As[tm+8][k], a2 = As[tm+16][k], a3 = As[tm+24][k];
      float wv[7];
      #pragma unroll
      for (int j = 0; j < 7; ++j) wv[j] = Ws[tn + 32*j][k];
      #pragma unroll
      for (int j = 0; j < 7; ++j){
        acc[0][j] = fmaf(a0, wv[j], acc[0][j]);
        acc[1][j] = fmaf(a1, wv[j], acc[1][j]);
        acc[2][j] = fmaf(a2, wv[j], acc[2][j]);
        acc[3][j] = fmaf(a3, wv[j], acc[3][j]);
      }
    }
  }
  #pragma unroll
  for (int i = 0; i < 4; ++i){
    size_t m = (size_t)m0 + tm + 8*i;
    #pragma unroll
    for (int j = 0; j < 7; ++j){
      int n = tn + 32*j;
      if (n < 200) Epost[m*STATE_ + n] = acc[i][j] + post1_b[n];
    }
  }
}

// ---------------- kernel 3: sequential core ----------------
// 256 blocks x 256 threads; block handles rows {2*blk, 2*blk+1} through all T steps.
__global__ __launch_bounds__(256, 1) void core_kernel(
    const float* __restrict__ u,
    const float* __restrict__ lat_act_b,
    const float* __restrict__ gru_bih,
    const float* __restrict__ gru_bhh,
    const float* __restrict__ post_m_b,
    const __hip_bfloat16* __restrict__ wbuf,
    const float* __restrict__ Epost,
    float* __restrict__ out_states,
    float* __restrict__ out_qm,
    float* __restrict__ zq_store)   // may be null
{
  const int tid  = threadIdx.x;
  const int row0 = blockIdx.x * 2;

  const __hip_bfloat16* Wla = wbuf + WOFF_LA;
  const __hip_bfloat16* Wih = wbuf + WOFF_IH;
  const __hip_bfloat16* Whh = wbuf + WOFF_HH;
  const __hip_bfloat16* Wp1 = wbuf + WOFF_P1;
  const __hip_bfloat16* Wpm = wbuf + WOFF_PM;

  __shared__ __align__(16) float h[2][STATE_];
  __shared__ __align__(16) float xv[2][40];       // [ s(30) | u(6) | pad0(4) ]
  __shared__ __align__(16) float xact[2][STATE_];
  __shared__ __align__(16) float zq[2][STATE_];
  __shared__ float gi[2][3*STATE_];
  __shared__ float gh[2][3*STATE_];
  __shared__ float bih_s[3*STATE_], bhh_s[3*STATE_], latb_s[STATE_], pmb_s[LATENT_];

  for (int i = tid; i < STATE_; i += 256){ h[0][i]=0.f; h[1][i]=0.f; latb_s[i]=lat_act_b[i]; }
  for (int i = tid; i < 3*STATE_; i += 256){ bih_s[i]=gru_bih[i]; bhh_s[i]=gru_bhh[i]; }
  if (tid < LATENT_){ pmb_s[tid]=post_m_b[tid]; }
  if (tid < 40){ xv[0][tid]=0.f; xv[1][tid]=0.f; }   // s0 = 0, pad = 0
  __syncthreads();

  for (int t = 0; t < T_; ++t){
    // stage u_t into xv[r][30..35]
    if (tid < 12){
      int r = tid / 6, k = tid % 6;
      xv[r][LATENT_ + k] = u[((size_t)(row0 + r)*T_ + t)*ACT_ + k];
    }
    __syncthreads();

    // x = relu([s,a] @ Wla.T + b)
    if (tid < STATE_){
      float a0 = latb_s[tid], a1 = a0;
      dot2bf<40>(Wla + tid*40, xv[0], xv[1], a0, a1);
      xact[0][tid] = fmaxf(a0, 0.f);
      xact[1][tid] = fmaxf(a1, 0.f);
    }
    __syncthreads();

    // gi = x @ Wih.T + bih ; gh = h @ Whh.T + bhh
    for (int n = tid; n < 3*STATE_; n += 256){
      float i0 = bih_s[n], i1 = i0;
      dot2bf<STATE_>(Wih + n*STATE_, xact[0], xact[1], i0, i1);
      gi[0][n] = i0; gi[1][n] = i1;
      float g0 = bhh_s[n], g1 = g0;
      dot2bf<STATE_>(Whh + n*STATE_, h[0], h[1], g0, g1);
      gh[0][n] = g0; gh[1][n] = g1;
    }
    __syncthreads();

    // GRU gate -> h_new, store states
    if (tid < STATE_){
      #pragma unroll
      for (int r = 0; r < 2; ++r){
        float rg = sigmoidf_(gi[r][tid] + gh[r][tid]);
        float zg = sigmoidf_(gi[r][STATE_ + tid] + gh[r][STATE_ + tid]);
        float ng = tanhf(gi[r][2*STATE_ + tid] + rg * gh[r][2*STATE_ + tid]);
        float hn = (1.f - zg) * ng + zg * h[r][tid];
        h[r][tid] = hn;
        out_states[((size_t)t*B_ + row0 + r)*STATE_ + tid] = hn;
      }
    }
    __syncthreads();

    // zq = relu(h_new @ Wp1h.T + Epost)
    if (tid < STATE_){
      float a0 = Epost[((size_t)t*B_ + row0    )*STATE_ + tid];
      float a1 = Epost[((size_t)t*B_ + row0 + 1)*STATE_ + tid];
      dot2bf<STATE_>(Wp1 + tid*STATE_, h[0], h[1], a0, a1);
      float z0 = fmaxf(a0, 0.f), z1 = fmaxf(a1, 0.f);
      zq[0][tid] = z0; zq[1][tid] = z1;
      if (zq_store){
        zq_store[((size_t)t*B_ + row0    )*STATE_ + tid] = z0;
        zq_store[((size_t)t*B_ + row0 + 1)*STATE_ + tid] = z1;
      }
    }
    __syncthreads();

    // qm = zq @ Wpm.T + b ; also next-step s
    if (tid < LATENT_){
      float a0 = pmb_s[tid], a1 = a0;
      dot2bf<STATE_>(Wpm + tid*STATE_, zq[0], zq[1], a0, a1);
      out_qm[((size_t)t*B_ + row0    )*LATENT_ + tid] = a0;
      out_qm[((size_t)t*B_ + row0 + 1)*LATENT_ + tid] = a1;
      xv[0][tid] = a0; xv[1][tid] = a1;
    }
    __syncthreads();
  }
}

// ---------------- kernel 4: parallel epilogue (prior branch + qs head) ----------------
__global__ __launch_bounds__(256, 4) void phasec_kernel(
    const float* __restrict__ states,
    const float* __restrict__ Epost,
    const float* __restrict__ zq_in,       // may be null -> recompute
    const float* __restrict__ post1_W,
    const float* __restrict__ prior1_W, const float* __restrict__ prior1_b,
    const float* __restrict__ prior_m_W, const float* __restrict__ prior_m_b,
    const float* __restrict__ prior_s_W, const float* __restrict__ prior_s_b,
    const float* __restrict__ post_s_W,  const float* __restrict__ post_s_b,
    float* __restrict__ pm, float* __restrict__ ps, float* __restrict__ qs,
    int recompute)
{
  __shared__ __align__(16) float st[16][STATE_];
  __shared__ __align__(16) float zp[16][STATE_];
  __shared__ __align__(16) float zqs[16][STATE_];
  const int tid = threadIdx.x;
  const size_t m0 = (size_t)blockIdx.x * 16;

  for (int i = tid; i < 16*STATE_/4; i += 256){
    int r = i / 50, c = (i % 50) * 4;
    *(float4*)&st[r][c] = *(const float4*)(states + (m0 + r)*STATE_ + c);
    if (!recompute)
      *(float4*)&zqs[r][c] = *(const float4*)(zq_in + (m0 + r)*STATE_ + c);
  }
  __syncthreads();

  for (int i = tid; i < 16*STATE_; i += 256){
    int r = i / STATE_, j = i % STATE_;
    float a = prior1_b[j] + dotf32_200(prior1_W + (size_t)j*STATE_, st[r]);
    zp[r][j] = fmaxf(a, 0.f);
    if (recompute){
      float b = Epost[(m0 + r)*STATE_ + j] + dotf32_200(post1_W + (size_t)j*1224, st[r]);
      zqs[r][j] = fmaxf(b, 0.f);
    }
  }
  __syncthreads();

  for (int i = tid; i < 16*3*LATENT_; i += 256){   // 1440 head outputs
    int r = i / (3*LATENT_);
    int rem = i % (3*LATENT_);
    int head = rem / LATENT_, l = rem % LATENT_;
    size_t m = m0 + r;
    const float* wsel = (head == 0) ? prior_m_W : (head == 1) ? prior_s_W : post_s_W;
    const float* bsel = (head == 0) ? prior_m_b : (head == 1) ? prior_s_b : post_s_b;
    const float* vsel = (head == 2) ? zqs[r] : zp[r];
    float a = bsel[l] + dotf32_200(wsel + (size_t)l*STATE_, vsel);
    if (head != 0) a = stdf_(a);
    float* osel = (head == 0) ? pm : (head == 1) ? ps : qs;
    osel[m*LATENT_ + l] = a;
  }
}

// ---------------- launcher ----------------
extern "C" void kernel_launch(void* const* d_in, const int* in_sizes, int n_in,
                              void* d_out, int out_size, void* d_ws, size_t ws_size,
                              hipStream_t stream)
{
  const float* e         = (const float*)d_in[0];
  const float* u         = (const float*)d_in[1];
  const float* lat_act_W = (const float*)d_in[2];
  const float* lat_act_b = (const float*)d_in[3];
  const float* gru_Wih   = (const float*)d_in[4];
  const float* gru_Whh   = (const float*)d_in[5];
  const float* gru_bih   = (const float*)d_in[6];
  const float* gru_bhh   = (const float*)d_in[7];
  const float* prior1_W  = (const float*)d_in[8];
  const float* prior1_b  = (const float*)d_in[9];
  const float* prior_m_W = (const float*)d_in[10];
  const float* prior_m_b = (const float*)d_in[11];
  const float* prior_s_W = (const float*)d_in[12];
  const float* prior_s_b = (const float*)d_in[13];
  const float* post1_W   = (const float*)d_in[14];
  const float* post1_b   = (const float*)d_in[15];
  const float* post_m_W  = (const float*)d_in[16];
  const float* post_m_b  = (const float*)d_in[17];
  const float* post_s_W  = (const float*)d_in[18];
  const float* post_s_b  = (const float*)d_in[19];

  float* out    = (float*)d_out;
  float* states = out;                      // [100][512][200]
  float* pm     = out + 10240000;           // [100][512][30]
  float* ps     = out + 11776000;
  float* qm     = out + 13312000;
  float* qs     = out + 14848000;

  const size_t EPOST_ELEMS = (size_t)T_ * B_ * STATE_;   // 10,240,000
  const size_t ZQ_ELEMS    = EPOST_ELEMS;
  bool store_zq = ws_size >= (EPOST_ELEMS + ZQ_ELEMS) * sizeof(float) + (size_t)WTOT * 2;

  float* Epost = (float*)d_ws;
  float* zqbuf = store_zq ? (Epost + EPOST_ELEMS) : nullptr;
  __hip_bfloat16* wbuf = (__hip_bfloat16*)((char*)d_ws +
      (store_zq ? (EPOST_ELEMS + ZQ_ELEMS) * sizeof(float) : EPOST_ELEMS * sizeof(float)));

  hipLaunchKernelGGL(prep_kernel, dim3((WTOT + 255) / 256), dim3(256), 0, stream,
                     lat_act_W, gru_Wih, gru_Whh, post1_W, post_m_W, wbuf);

  hipLaunchKernelGGL(epost_kernel, dim3((T_ * B_) / 32), dim3(256), 0, stream,
                     e, post1_W, post1_b, Epost);

  hipLaunchKernelGGL(core_kernel, dim3(B_ / 2), dim3(256), 0, stream,
                     u, lat_act_b, gru_bih, gru_bhh, post_m_b, wbuf, Epost,
                     states, qm, zqbuf);

  hipLaunchKernelGGL(phasec_kernel, dim3((T_ * B_) / 16), dim3(256), 0, stream,
                     states, Epost, zqbuf, post1_W,
                     prior1_W, prior1_b, prior_m_W, prior_m_b,
                     prior_s_W, prior_s_b, post_s_W, post_s_b,
                     pm, ps, qs, store_zq ? 0 : 1);
}

// Round 3
// 3571.989 us; speedup vs baseline: 1.2528x; 1.2528x over previous
//
#include <hip/hip_runtime.h>
#include <cstdint>

typedef unsigned int u32;
typedef unsigned short u16;
typedef short bf16x8 __attribute__((ext_vector_type(8)));
typedef float f32x4 __attribute__((ext_vector_type(4)));

#define Bq 512
#define Tq 100
#define NST 200
#define NLAT 30
#define NEMB 1024
#define NACT 6

// packed weight tile offsets (tile = 16n x 32k = 512 bf16 = 1KB, B-fragment order)
#define T_LA   0      // 13 nt x 2 kt   (lat_act_W, K padded 36->64)
#define T_IH   26     // 39 nt x 7 kt   (gru_Wih rows reordered: (group g, gate) triples)
#define T_HH   299    // 39 nt x 7 kt
#define T_P1   572    // 13 nt x 7 kt   (post1_W[:, :200])
#define T_PM   663    //  2 nt x 7 kt   (post_m_W)
#define T_POST 677    // 13 nt x 32 kt  (post1_W[:, 200:], K=1024)
#define T_PR1  1093   // 13 nt x 7 kt   (prior1_W)
#define T_TOT  1184
#define NFRAG  (T_TOT * 64)

__device__ __forceinline__ u16 f2bf(float f){
  u32 x = __float_as_uint(f);
  return (u16)((x + 0x7FFFu + ((x >> 16) & 1u)) >> 16);
}
__device__ __forceinline__ float bf2f(u16 h){ return __uint_as_float(((u32)h) << 16); }

__device__ __forceinline__ float sigm(float x){ return 1.0f / (1.0f + expf(-x)); }
__device__ __forceinline__ float stdf_(float x){
  float sp = fmaxf(x, 0.f) + log1pf(expf(-fabsf(x))) + 0.1f;
  return fminf(fmaxf(sp, 1e-6f), 10.0f);
}

// ---------------- kernel 1: pack weights into MFMA B-fragment tiles ----------------
__global__ __launch_bounds__(256) void prep2(
    const float* __restrict__ lat_act_W,
    const float* __restrict__ gru_Wih,
    const float* __restrict__ gru_Whh,
    const float* __restrict__ post1_W,
    const float* __restrict__ post_m_W,
    const float* __restrict__ prior1_W,
    u16* __restrict__ wbuf)
{
  int gid = blockIdx.x * 256 + threadIdx.x;
  if (gid >= NFRAG) return;
  int tile = gid >> 6, lane = gid & 63;
  int nl = lane & 15, qq = lane >> 4;
  const float* src = nullptr;
  long stride = 0; int row = 0, kbase = 0, kmax = 0, coff = 0; bool vn = false;
  if (tile < T_IH){                       // LA
    int lt = tile, nt = lt >> 1, kt = lt & 1;
    row = nt*16 + nl; vn = row < 200; kbase = kt*32 + qq*8; kmax = 36;
    src = lat_act_W; stride = 36;
  } else if (tile < T_HH){                // IH (gate-triple reordered)
    int lt = tile - T_IH, nt = lt / 7, kt = lt - nt*7;
    int g = nt / 3, gate = nt - g*3, nn = g*16 + nl;
    vn = nn < 200; row = gate*200 + nn; kbase = kt*32 + qq*8; kmax = 200;
    src = gru_Wih; stride = 200;
  } else if (tile < T_P1){                // HH
    int lt = tile - T_HH, nt = lt / 7, kt = lt - nt*7;
    int g = nt / 3, gate = nt - g*3, nn = g*16 + nl;
    vn = nn < 200; row = gate*200 + nn; kbase = kt*32 + qq*8; kmax = 200;
    src = gru_Whh; stride = 200;
  } else if (tile < T_PM){                // P1 (post1 h-part)
    int lt = tile - T_P1, nt = lt / 7, kt = lt - nt*7;
    row = nt*16 + nl; vn = row < 200; kbase = kt*32 + qq*8; kmax = 200;
    src = post1_W; stride = 1224;
  } else if (tile < T_POST){              // PM
    int lt = tile - T_PM, nt = lt / 7, kt = lt - nt*7;
    row = nt*16 + nl; vn = row < 30; kbase = kt*32 + qq*8; kmax = 200;
    src = post_m_W; stride = 200;
  } else if (tile < T_PR1){               // POST (post1 e-part, K=1024)
    int lt = tile - T_POST, nt = lt >> 5, kt = lt & 31;
    row = nt*16 + nl; vn = row < 200; kbase = kt*32 + qq*8; kmax = 1024; coff = 200;
    src = post1_W; stride = 1224;
  } else {                                // PR1
    int lt = tile - T_PR1, nt = lt / 7, kt = lt - nt*7;
    row = nt*16 + nl; vn = row < 200; kbase = kt*32 + qq*8; kmax = 200;
    src = prior1_W; stride = 200;
  }
  __align__(16) u16 ov[8];
  #pragma unroll
  for (int j = 0; j < 8; ++j){
    int k = kbase + j;
    float v = (vn && k < kmax) ? src[(size_t)row*stride + coff + k] : 0.f;
    ov[j] = f2bf(v);
  }
  *(uint4*)(wbuf + (size_t)gid*8) = *(const uint4*)ov;
}

// ---------------- kernel 2: Epost = e[:,1:] @ post1_W[:,200:].T + post1_b (bf16 out) ----------------
__global__ __launch_bounds__(256) void epost_kernel(
    const float* __restrict__ e,
    const float* __restrict__ post1_b,
    const u16* __restrict__ wbuf,
    u16* __restrict__ Epost)
{
  __shared__ __align__(16) u16 Ab[2][64][40];
  const int tid = threadIdx.x;
  const int wave = tid >> 6, lane = tid & 63, nl = lane & 15, q = lane >> 4;
  const int m0 = blockIdx.x * 64;
  const int tt = m0 >> 9;
  const int b0 = m0 & 511;
  const u16* wPOST = wbuf + (size_t)T_POST * 512;

  f32x4 zero4 = {0.f, 0.f, 0.f, 0.f};
  f32x4 acc[13];
  #pragma unroll
  for (int i = 0; i < 13; ++i) acc[i] = zero4;

  const int sr = tid >> 2;
  const int sc = (tid & 3) * 8;
  const float* esrc = e + ((size_t)(b0 + sr)*(Tq + 1) + (tt + 1))*NEMB + sc;

  {
    float4 f0 = *(const float4*)(esrc);
    float4 f1 = *(const float4*)(esrc + 4);
    bf16x8 v;
    v[0]=(short)f2bf(f0.x); v[1]=(short)f2bf(f0.y); v[2]=(short)f2bf(f0.z); v[3]=(short)f2bf(f0.w);
    v[4]=(short)f2bf(f1.x); v[5]=(short)f2bf(f1.y); v[6]=(short)f2bf(f1.z); v[7]=(short)f2bf(f1.w);
    *(bf16x8*)(&Ab[0][sr][sc]) = v;
  }
  __syncthreads();
  for (int kt = 0; kt < 32; ++kt){
    int cur = kt & 1;
    if (kt + 1 < 32){
      const float* p = esrc + (size_t)(kt + 1)*32;
      float4 f0 = *(const float4*)(p);
      float4 f1 = *(const float4*)(p + 4);
      bf16x8 v;
      v[0]=(short)f2bf(f0.x); v[1]=(short)f2bf(f0.y); v[2]=(short)f2bf(f0.z); v[3]=(short)f2bf(f0.w);
      v[4]=(short)f2bf(f1.x); v[5]=(short)f2bf(f1.y); v[6]=(short)f2bf(f1.z); v[7]=(short)f2bf(f1.w);
      *(bf16x8*)(&Ab[cur ^ 1][sr][sc]) = v;
    }
    bf16x8 afr = *(const bf16x8*)(&Ab[cur][wave*16 + nl][q*8]);
    #pragma unroll
    for (int nt = 0; nt < 13; ++nt){
      bf16x8 b = *(const bf16x8*)(wPOST + (((size_t)(nt*32 + kt)) << 9) + lane*8);
      acc[nt] = __builtin_amdgcn_mfma_f32_16x16x32_bf16(afr, b, acc[nt], 0, 0, 0);
    }
    __syncthreads();
  }
  #pragma unroll
  for (int nt = 0; nt < 13; ++nt){
    int n = nt*16 + nl;
    if (n < 200){
      float bb = post1_b[n];
      #pragma unroll
      for (int r = 0; r < 4; ++r){
        int m = m0 + wave*16 + q*4 + r;
        Epost[(size_t)m*NST + n] = f2bf(acc[nt][r] + bb);
      }
    }
  }
}

// ---------------- kernel 3: sequential MFMA core (32 blocks x 16 rows, 8 waves) ----------------
// Weights are consumed once per step by exactly one wave -> direct global->VGPR
// B-fragment loads (compiler-managed waitcnt); no LDS staging, no manual vmcnt.
__global__ __launch_bounds__(512, 2) void core_kernel(
    const float* __restrict__ u,
    const float* __restrict__ lat_act_b,
    const float* __restrict__ gru_bih,
    const float* __restrict__ gru_bhh,
    const float* __restrict__ post_m_b,
    const u16* __restrict__ wbuf,
    const u16* __restrict__ Epost,
    float* __restrict__ out_states,
    float* __restrict__ out_qm)
{
  __shared__ __align__(16) u16 xs[16][72];        // [ s(30) | u(6) | pad->64 ] bf16
  __shared__ __align__(16) u16 xb[16][232];       // lat output bf16, K-pad 224
  __shared__ __align__(16) u16 hb[2][16][232];    // h bf16 mirror, DOUBLE-BUFFERED (race fix)
  __shared__ __align__(16) u16 zqb[16][232];      // zq bf16
  __shared__ float hf[16][200];                   // fp32 master h (same-lane read/write only)
  __shared__ float latb_s[208];
  __shared__ float bih_s[608];
  __shared__ float bhh_s[608];
  __shared__ float pmb_s[32];

  const int tid  = threadIdx.x;
  const int wave = tid >> 6;
  const int lane = tid & 63;
  const int nl   = lane & 15;
  const int q    = lane >> 4;
  const int row0 = blockIdx.x * 16;

  const u16* wLA = wbuf + (size_t)T_LA * 512;
  const u16* wIH = wbuf + (size_t)T_IH * 512;
  const u16* wHH = wbuf + (size_t)T_HH * 512;
  const u16* wP1 = wbuf + (size_t)T_P1 * 512;
  const u16* wPM = wbuf + (size_t)T_PM * 512;

  for (int i = tid; i < 16*72;  i += 512) ((u16*)xs)[i] = 0;
  for (int i = tid; i < 16*232; i += 512){
    ((u16*)xb)[i] = 0; ((u16*)hb[0])[i] = 0; ((u16*)hb[1])[i] = 0; ((u16*)zqb)[i] = 0;
  }
  for (int i = tid; i < 16*200; i += 512) ((float*)hf)[i] = 0.f;
  for (int i = tid; i < 608; i += 512){              // FIX: full strided init (R2 left 512..607 garbage)
    bih_s[i] = (i < 600) ? gru_bih[i] : 0.f;
    bhh_s[i] = (i < 600) ? gru_bhh[i] : 0.f;
  }
  if (tid < 208) latb_s[tid] = (tid < 200) ? lat_act_b[tid] : 0.f;
  if (tid >= 480){ int i = tid - 480; pmb_s[i] = (i < 30) ? post_m_b[i] : 0.f; }
  __syncthreads();

  const int ur = tid / 6, uk = tid - ur*6;
  const bool uth = (tid < 96);
  float u_reg = uth ? u[((size_t)(row0 + ur)*Tq + 0)*NACT + uk] : 0.f;

  const int nt0 = wave;
  const int nt1 = wave + 8;
  const bool two = (nt1 < 13);

  for (int t = 0; t < Tq; ++t){
    const int pb = t & 1;
    if (uth) xs[ur][30 + uk] = f2bf(u_reg);
    __syncthreads();                                     // B0

    // ---- LAT: x = relu([s,a] @ Wla^T + b) ----
    {
      bf16x8 axs[2];
      axs[0] = *(const bf16x8*)(&xs[nl][q*8]);
      axs[1] = *(const bf16x8*)(&xs[nl][32 + q*8]);
      for (int c = 0; c < (two ? 2 : 1); ++c){
        int nt = c ? nt1 : nt0;
        f32x4 a = {0.f, 0.f, 0.f, 0.f};
        #pragma unroll
        for (int kt = 0; kt < 2; ++kt){
          bf16x8 b = *(const bf16x8*)(wLA + (((size_t)(nt*2 + kt)) << 9) + lane*8);
          a = __builtin_amdgcn_mfma_f32_16x16x32_bf16(axs[kt], b, a, 0, 0, 0);
        }
        int n = nt*16 + nl;
        if (n < 200){
          #pragma unroll
          for (int r = 0; r < 4; ++r)
            xb[q*4 + r][n] = f2bf(fmaxf(a[r] + latb_s[n], 0.f));
        }
      }
    }
    __syncthreads();                                     // B1

    // ---- GATES: GRU, gi/gh fused in registers; reads hb[pb], writes hb[pb^1] ----
    {
      bf16x8 ax[7], ah[7];
      #pragma unroll
      for (int kt = 0; kt < 7; ++kt){
        ax[kt] = *(const bf16x8*)(&xb[nl][kt*32 + q*8]);
        ah[kt] = *(const bf16x8*)(&hb[pb][nl][kt*32 + q*8]);
      }
      // prefetch Epost slice for P1 + next-step u (plain loads, compiler-managed)
      u16 ep0[4] = {0,0,0,0}, ep1[4] = {0,0,0,0};
      {
        int n0 = nt0*16 + nl;
        int n1 = nt1*16 + nl;
        #pragma unroll
        for (int r = 0; r < 4; ++r){
          int m = q*4 + r;
          if (n0 < 200) ep0[r] = Epost[((size_t)t*Bq + row0 + m)*NST + n0];
          if (two && n1 < 200) ep1[r] = Epost[((size_t)t*Bq + row0 + m)*NST + n1];
        }
      }
      if (uth && t + 1 < Tq) u_reg = u[((size_t)(row0 + ur)*Tq + (t + 1))*NACT + uk];

      for (int c = 0; c < ((wave < 5) ? 2 : 1); ++c){
        int g = c ? (wave + 8) : wave;
        f32x4 acc[3][2];
        #pragma unroll
        for (int gate = 0; gate < 3; ++gate)
        #pragma unroll
        for (int s = 0; s < 2; ++s){
          const u16* base = s ? wHH : wIH;
          f32x4 a = {0.f, 0.f, 0.f, 0.f};
          #pragma unroll
          for (int kt = 0; kt < 7; ++kt){
            bf16x8 b = *(const bf16x8*)(base + (((size_t)((g*3 + gate)*7 + kt)) << 9) + lane*8);
            a = __builtin_amdgcn_mfma_f32_16x16x32_bf16(s ? ah[kt] : ax[kt], b, a, 0, 0, 0);
          }
          acc[gate][s] = a;
        }
        int n = g*16 + nl;
        if (n < 200){
          #pragma unroll
          for (int r = 0; r < 4; ++r){
            int m = q*4 + r;
            float rg = sigm(acc[0][0][r] + acc[0][1][r] + bih_s[n] + bhh_s[n]);
            float zg = sigm(acc[1][0][r] + acc[1][1][r] + bih_s[200 + n] + bhh_s[200 + n]);
            float ng = tanhf(acc[2][0][r] + bih_s[400 + n] + rg*(acc[2][1][r] + bhh_s[400 + n]));
            float hn = (1.f - zg)*ng + zg*hf[m][n];
            hf[m][n] = hn;
            hb[pb ^ 1][m][n] = f2bf(hn);
            out_states[((size_t)t*Bq + row0 + m)*NST + n] = hn;
          }
        }
      }
      __syncthreads();                                   // B2

      // ---- P1: zq = relu(h_new @ Wp1^T + Epost) ----
      bf16x8 ah2[7];
      #pragma unroll
      for (int kt = 0; kt < 7; ++kt)
        ah2[kt] = *(const bf16x8*)(&hb[pb ^ 1][nl][kt*32 + q*8]);
      for (int c = 0; c < (two ? 2 : 1); ++c){
        int nt = c ? nt1 : nt0;
        const u16* ep = c ? ep1 : ep0;
        f32x4 a = {0.f, 0.f, 0.f, 0.f};
        #pragma unroll
        for (int kt = 0; kt < 7; ++kt){
          bf16x8 b = *(const bf16x8*)(wP1 + (((size_t)(nt*7 + kt)) << 9) + lane*8);
          a = __builtin_amdgcn_mfma_f32_16x16x32_bf16(ah2[kt], b, a, 0, 0, 0);
        }
        int n = nt*16 + nl;
        if (n < 200){
          #pragma unroll
          for (int r = 0; r < 4; ++r)
            zqb[q*4 + r][n] = f2bf(fmaxf(a[r] + bf2f(ep[r]), 0.f));
        }
      }
    }
    __syncthreads();                                     // B3

    // ---- QM: qm = zq @ Wpm^T + b (feeds next-step s) ----
    if (wave < 2){
      bf16x8 az[7];
      #pragma unroll
      for (int kt = 0; kt < 7; ++kt)
        az[kt] = *(const bf16x8*)(&zqb[nl][kt*32 + q*8]);
      f32x4 a = {0.f, 0.f, 0.f, 0.f};
      #pragma unroll
      for (int kt = 0; kt < 7; ++kt){
        bf16x8 b = *(const bf16x8*)(wPM + (((size_t)(wave*7 + kt)) << 9) + lane*8);
        a = __builtin_amdgcn_mfma_f32_16x16x32_bf16(az[kt], b, a, 0, 0, 0);
      }
      int n = wave*16 + nl;
      if (n < 30){
        #pragma unroll
        for (int r = 0; r < 4; ++r){
          int m = q*4 + r;
          float v = a[r] + pmb_s[n];
          out_qm[((size_t)t*Bq + row0 + m)*NLAT + n] = v;
          xs[m][n] = f2bf(v);
        }
      }
    }
    // loop back; B0 of next iteration synchronizes
  }
}

// ---------------- kernel 4: prior branch + qs head ----------------
__global__ __launch_bounds__(256) void phasec_kernel(
    const float* __restrict__ states,
    const u16* __restrict__ Epost,
    const u16* __restrict__ wbuf,
    const float* __restrict__ prior1_b,
    const float* __restrict__ prior_m_W, const float* __restrict__ prior_m_b,
    const float* __restrict__ prior_s_W, const float* __restrict__ prior_s_b,
    const float* __restrict__ post_s_W,  const float* __restrict__ post_s_b,
    float* __restrict__ pm, float* __restrict__ ps, float* __restrict__ qs)
{
  __shared__ __align__(16) u16 stb[32][232];
  __shared__ float zp[32][208];
  __shared__ float zqf[32][208];
  const int tid = threadIdx.x, wave = tid >> 6, lane = tid & 63, nl = lane & 15, q = lane >> 4;
  const size_t m0 = (size_t)blockIdx.x * 32;
  const u16* wP1  = wbuf + (size_t)T_P1 * 512;
  const u16* wPR1 = wbuf + (size_t)T_PR1 * 512;

  for (int i = tid; i < 32*200; i += 256){
    int r = i / 200, c = i - r*200;
    stb[r][c] = f2bf(states[(m0 + r)*NST + c]);
  }
  for (int i = tid; i < 32*32; i += 256){
    int r = i >> 5, c = i & 31;
    stb[r][200 + c] = 0;
  }
  __syncthreads();

  {
    const int rowb = (wave & 1) * 16;
    const bool doZQ = (wave >= 2);
    const u16* wmat = doZQ ? wP1 : wPR1;
    bf16x8 a7[7];
    #pragma unroll
    for (int kt = 0; kt < 7; ++kt)
      a7[kt] = *(const bf16x8*)(&stb[rowb + nl][kt*32 + q*8]);
    for (int nt = 0; nt < 13; ++nt){
      f32x4 a = {0.f, 0.f, 0.f, 0.f};
      #pragma unroll
      for (int kt = 0; kt < 7; ++kt){
        bf16x8 b = *(const bf16x8*)(wmat + (((size_t)(nt*7 + kt)) << 9) + lane*8);
        a = __builtin_amdgcn_mfma_f32_16x16x32_bf16(a7[kt], b, a, 0, 0, 0);
      }
      int n = nt*16 + nl;
      if (n < 200){
        #pragma unroll
        for (int r = 0; r < 4; ++r){
          int m = rowb + q*4 + r;
          if (doZQ){
            float v = a[r] + bf2f(Epost[(m0 + m)*NST + n]);
            zqf[m][n] = fmaxf(v, 0.f);
          } else {
            float v = a[r] + prior1_b[n];
            zp[m][n] = fmaxf(v, 0.f);
          }
        }
      }
    }
  }
  __syncthreads();

  for (int i = tid; i < 32*90; i += 256){
    int r = i / 90, rem = i - r*90;
    int head = rem / 30, l = rem - head*30;
    const float* wrow = (head == 0 ? prior_m_W : head == 1 ? prior_s_W : post_s_W) + (size_t)l*NST;
    const float* vec = (head == 2) ? &zqf[r][0] : &zp[r][0];
    float acc = 0.f;
    #pragma unroll 10
    for (int c = 0; c < 50; ++c){
      float4 wv = *(const float4*)(wrow + c*4);
      acc = fmaf(wv.x, vec[c*4 + 0], acc);
      acc = fmaf(wv.y, vec[c*4 + 1], acc);
      acc = fmaf(wv.z, vec[c*4 + 2], acc);
      acc = fmaf(wv.w, vec[c*4 + 3], acc);
    }
    float bias = (head == 0 ? prior_m_b : head == 1 ? prior_s_b : post_s_b)[l];
    float v = acc + bias;
    if (head) v = stdf_(v);
    float* o = head == 0 ? pm : head == 1 ? ps : qs;
    o[(m0 + r)*NLAT + l] = v;
  }
}

// ---------------- launcher ----------------
extern "C" void kernel_launch(void* const* d_in, const int* in_sizes, int n_in,
                              void* d_out, int out_size, void* d_ws, size_t ws_size,
                              hipStream_t stream)
{
  const float* e         = (const float*)d_in[0];
  const float* u         = (const float*)d_in[1];
  const float* lat_act_W = (const float*)d_in[2];
  const float* lat_act_b = (const float*)d_in[3];
  const float* gru_Wih   = (const float*)d_in[4];
  const float* gru_Whh   = (const float*)d_in[5];
  const float* gru_bih   = (const float*)d_in[6];
  const float* gru_bhh   = (const float*)d_in[7];
  const float* prior1_W  = (const float*)d_in[8];
  const float* prior1_b  = (const float*)d_in[9];
  const float* prior_m_W = (const float*)d_in[10];
  const float* prior_m_b = (const float*)d_in[11];
  const float* prior_s_W = (const float*)d_in[12];
  const float* prior_s_b = (const float*)d_in[13];
  const float* post1_W   = (const float*)d_in[14];
  const float* post1_b   = (const float*)d_in[15];
  const float* post_m_W  = (const float*)d_in[16];
  const float* post_m_b  = (const float*)d_in[17];
  const float* post_s_W  = (const float*)d_in[18];
  const float* post_s_b  = (const float*)d_in[19];

  float* out    = (float*)d_out;
  float* states = out;                       // [100][512][200]
  float* pm     = out + 10240000;
  float* ps     = out + 11776000;
  float* qm     = out + 13312000;
  float* qs     = out + 14848000;

  u16* Epost = (u16*)d_ws;                               // 10,240,000 bf16 = 20.48 MB
  u16* wbuf  = (u16*)((char*)d_ws + 20480000);           // 1.21 MB packed weights

  hipLaunchKernelGGL(prep2, dim3((NFRAG + 255) / 256), dim3(256), 0, stream,
                     lat_act_W, gru_Wih, gru_Whh, post1_W, post_m_W, prior1_W, wbuf);

  hipLaunchKernelGGL(epost_kernel, dim3(800), dim3(256), 0, stream,
                     e, post1_b, wbuf, Epost);

  hipLaunchKernelGGL(core_kernel, dim3(32), dim3(512), 0, stream,
                     u, lat_act_b, gru_bih, gru_bhh, post_m_b, wbuf, Epost, states, qm);

  hipLaunchKernelGGL(phasec_kernel, dim3(1600), dim3(256), 0, stream,
                     states, Epost, wbuf, prior1_b,
                     prior_m_W, prior_m_b, prior_s_W, prior_s_b,
                     post_s_W, post_s_b, pm, ps, qs);
}